// Round 6
// baseline (100.845 us; speedup 1.0000x reference)
//
#include <hip/hip_runtime.h>
#include <math.h>
#include <stdint.h>

// H[r,t] = (1/128) * sum_l alpha_l * exp(j*pi*r*sin(theta_r_l)) * exp(-j*pi*t*sin(theta_t_l))
// Output: out_size == 1024*1024 -> Re(H).
// Re(H) = A * B^T with K interleaved as (re,im) pairs per ray:
//   A[r][2l]   = C*(ar*cos(phi) - ai*sin(phi)),  phi = pi*r*sin(theta_r_l), C = 1/128
//   A[r][2l+1] = C*(ar*sin(phi) + ai*cos(phi))
//   B[t][2l]   = cos(psi),  psi = pi*t*sin(theta_t_l)
//   B[t][2l+1] = sin(psi)
// Gen-in-place GEMM: A fragments generated into LDS (fragment-linear, conflict
// free); B fragments generated DIRECTLY IN REGISTERS (gen slot layout == MFMA
// b-frag layout). Phase chains: one sincos per (ray, side), further fragments
// via precomputed per-ray complex deltas (e^{j*pi*64*sr}, e^{j*pi*16*st}).
// fp32 split-K partials reduced by a second kernel.

#define N_T 1024
#define N_R 1024
#define L_RAYS 8192

#define BM 128
#define BN 128
#define BK 64
#define NTILES 64           // 8x8 tile grid
#define SPLITK 8
#define RAYS_PER_BLK 1024   // L_RAYS / SPLITK
#define KSTEPS 32           // RAYS_PER_BLK*2 / BK

typedef __attribute__((ext_vector_type(8))) short bf16x8;
typedef __attribute__((ext_vector_type(4))) float f32x4;
typedef __attribute__((ext_vector_type(4))) unsigned int u32x4;

static __device__ __forceinline__ unsigned short f2bf(float x) {
    unsigned u = __builtin_bit_cast(unsigned, x);
    unsigned r = (u + 0x7FFFu + ((u >> 16) & 1u)) >> 16;
    return (unsigned short)r;
}

static __device__ __forceinline__ unsigned pk_bf16(float lo, float hi) {
    unsigned o;
    asm("v_cvt_pk_bf16_f32 %0, %1, %2" : "=v"(o) : "v"(lo), "v"(hi));
    return o;
}

// ------------------------------------------------------------- precompute
// pre1[l] = (0.5*sin_r, 0.5*sin_t, ar*C, ai*C)
// pre2[l] = (d64r.re, d64r.im, d16t.re, d16t.im)
//   d64r = e^{j*2pi*(32*sr)}  (A-row step +64),  d16t = e^{j*2pi*(8*st)} (B +16)
__global__ __launch_bounds__(256) void precomp_kernel(
    const float* __restrict__ alpha_re, const float* __restrict__ alpha_im,
    const float* __restrict__ theta_t, const float* __restrict__ theta_r,
    float4* __restrict__ pre1, float4* __restrict__ pre2)
{
    const int l = blockIdx.x * 256 + threadIdx.x;
    if (l >= L_RAYS) return;
    const float C = 0.0078125f;     // 1/128
    const float sr = sinf(theta_r[l]);
    const float st = sinf(theta_t[l]);
    pre1[l] = make_float4(0.5f * sr, 0.5f * st, alpha_re[l] * C, alpha_im[l] * C);
    float u1 = 32.0f * sr;  u1 -= rintf(u1);
    float u2 = 8.0f * st;   u2 -= rintf(u2);
    pre2[l] = make_float4(__builtin_amdgcn_cosf(u1), __builtin_amdgcn_sinf(u1),
                          __builtin_amdgcn_cosf(u2), __builtin_amdgcn_sinf(u2));
}

// ------------------------------------------------------------- fused GEMM
// grid = 64 tiles * SPLITK(8) = 512 blocks (2/CU), 256 threads (4 waves, 2x2).
// LDS (A only, 16 KB): fragment f of k-half h at bytes h*8192 + f*1024; lane
// slot s = row (f*16 + (s&15)), rays (s>>4)*4.. -> both ds_write_b128 and
// ds_read_b128 lane-linear: zero bank conflicts. B never touches LDS.
__global__ __launch_bounds__(256, 2) void fused_gemm_kernel(
    const float4* __restrict__ pre1, const float4* __restrict__ pre2,
    float* __restrict__ Pout)  // [SPLITK][N_R][N_T] fp32 partials
{
    __shared__ unsigned short As[BM * BK];   // 16 KB

    const int tid  = threadIdx.x;
    const int wave = tid >> 6;          // 0..3
    const int lane = tid & 63;
    const int bid  = blockIdx.x;
    const int tile = bid & (NTILES - 1);
    const int sk   = bid >> 6;          // split-K slice 0..7
    const int r0 = (tile >> 3) * BM;
    const int c0 = (tile & 7) * BN;

    const int k8   = lane >> 4;         // ray sub-group 0..3
    const int rsub = lane & 15;         // row within fragment
    const int wr = wave >> 1;           // 0..1: row half (64 rows)
    const int wc = wave & 1;            // 0..1: col half (64 cols)

    // A gen rows: frags {wave, wave+4} -> base row wave*16+rsub, chain +64
    const float rwA = (float)(r0 + wave * 16 + rsub);
    // B gen cols: frags {wc*4+n} -> base col wc*64+rsub, chain +16
    const float twB = (float)(c0 + wc * 64 + rsub);

    f32x4 acc[4][4];
    #pragma unroll
    for (int m = 0; m < 4; ++m)
        #pragma unroll
        for (int n = 0; n < 4; ++n)
            acc[m][n] = (f32x4){0.f, 0.f, 0.f, 0.f};

    const int ray_base0 = sk * RAYS_PER_BLK + (k8 << 2);

    float4 cp[2][4], cd[2][4];
    // prologue: params for kt=0
    #pragma unroll
    for (int h = 0; h < 2; ++h)
        #pragma unroll
        for (int j = 0; j < 4; ++j) {
            cp[h][j] = pre1[ray_base0 + h * 16 + j];
            cd[h][j] = pre2[ray_base0 + h * 16 + j];
        }

    char* Ab = reinterpret_cast<char*>(&As[0]);

    for (int kt = 0; kt < KSTEPS; ++kt) {
        // ---- generate: B fragments into registers, A fragments into oa[]
        unsigned oa[2][2][4];   // [h][chain q][j]
        bf16x8 breg[2][4];      // [h][n]
        #pragma unroll
        for (int h = 0; h < 2; ++h) {
            unsigned ob[4][4];  // [n][j]
            #pragma unroll
            for (int j = 0; j < 4; ++j) {
                const float4 p = cp[h][j];
                const float4 d = cd[h][j];
                // A base phasor (alpha folded), then chain by d64r = (d.x,d.y)
                float ua = rwA * p.x;  ua -= rintf(ua);
                const float asn = __builtin_amdgcn_sinf(ua);
                const float acs = __builtin_amdgcn_cosf(ua);
                const float re0 = p.z * acs - p.w * asn;
                const float im0 = p.z * asn + p.w * acs;
                oa[h][0][j] = pk_bf16(re0, im0);
                const float re1 = re0 * d.x - im0 * d.y;
                const float im1 = re0 * d.y + im0 * d.x;
                oa[h][1][j] = pk_bf16(re1, im1);
                // B base phasor, chain by d16t = (d.z,d.w)
                float ub = twB * p.y;  ub -= rintf(ub);
                const float bs0 = __builtin_amdgcn_sinf(ub);
                const float bc0 = __builtin_amdgcn_cosf(ub);
                ob[0][j] = pk_bf16(bc0, bs0);
                const float bc1 = bc0 * d.z - bs0 * d.w;
                const float bs1 = bc0 * d.w + bs0 * d.z;
                ob[1][j] = pk_bf16(bc1, bs1);
                const float bc2 = bc1 * d.z - bs1 * d.w;
                const float bs2 = bc1 * d.w + bs1 * d.z;
                ob[2][j] = pk_bf16(bc2, bs2);
                const float bc3 = bc2 * d.z - bs2 * d.w;
                const float bs3 = bc2 * d.w + bs2 * d.z;
                ob[3][j] = pk_bf16(bc3, bs3);
            }
            #pragma unroll
            for (int n = 0; n < 4; ++n) {
                const u32x4 t = (u32x4){ob[n][0], ob[n][1], ob[n][2], ob[n][3]};
                breg[h][n] = __builtin_bit_cast(bf16x8, t);
            }
        }

        __syncthreads();    // WAR: previous iteration's a-reads complete
        #pragma unroll
        for (int h = 0; h < 2; ++h) {
            *reinterpret_cast<u32x4*>(Ab + h * 8192 + (wave + 0) * 1024 + lane * 16)
                = (u32x4){oa[h][0][0], oa[h][0][1], oa[h][0][2], oa[h][0][3]};
            *reinterpret_cast<u32x4*>(Ab + h * 8192 + (wave + 4) * 1024 + lane * 16)
                = (u32x4){oa[h][1][0], oa[h][1][1], oa[h][1][2], oa[h][1][3]};
        }
        __syncthreads();    // A tile visible

        // prefetch next kt's ray params (completes under the MFMA phase)
        if (kt + 1 < KSTEPS) {
            const int rb = ray_base0 + (kt + 1) * 32;
            #pragma unroll
            for (int h = 0; h < 2; ++h)
                #pragma unroll
                for (int j = 0; j < 4; ++j) {
                    cp[h][j] = pre1[rb + h * 16 + j];
                    cd[h][j] = pre2[rb + h * 16 + j];
                }
        }

        // ---- consume: a from LDS, b from registers
        __builtin_amdgcn_s_setprio(1);
        #pragma unroll
        for (int h = 0; h < 2; ++h) {
            bf16x8 a[4];
            #pragma unroll
            for (int m = 0; m < 4; ++m)
                a[m] = *reinterpret_cast<const bf16x8*>(
                    Ab + h * 8192 + (wr * 4 + m) * 1024 + lane * 16);
            #pragma unroll
            for (int m = 0; m < 4; ++m)
                #pragma unroll
                for (int n = 0; n < 4; ++n)
                    acc[m][n] = __builtin_amdgcn_mfma_f32_16x16x32_bf16(
                        a[m], breg[h][n], acc[m][n], 0, 0, 0);
        }
        __builtin_amdgcn_s_setprio(0);
    }

    // C/D layout (m89/m91): col = lane&15, row = (lane>>4)*4 + reg
    float* P = Pout + (size_t)sk * (N_R * N_T);
    const int crow0 = r0 + wr * 64 + (lane >> 4) * 4;
    const int ccol0 = c0 + wc * 64 + (lane & 15);
    #pragma unroll
    for (int m = 0; m < 4; ++m)
        #pragma unroll
        for (int n = 0; n < 4; ++n)
            #pragma unroll
            for (int j = 0; j < 4; ++j)
                P[(size_t)(crow0 + m * 16 + j) * N_T + ccol0 + n * 16] = acc[m][n][j];
}

// ------------------------------------------------------------- split-K reduce
__global__ __launch_bounds__(256) void reduce_kernel(
    const f32x4* __restrict__ P, f32x4* __restrict__ out)
{
    const int i = blockIdx.x * 256 + threadIdx.x;   // over N_R*N_T/4
    const int n4 = (N_R * N_T) / 4;
    f32x4 s = P[i];
    #pragma unroll
    for (int sk = 1; sk < SPLITK; ++sk) s += P[(size_t)sk * n4 + i];
    out[i] = s;
}

// ------------------------------------------------------------- fp32 fallback
#define TILE 64
#define KC 32
__global__ __launch_bounds__(256) void geo_channel_fallback(
    const float* __restrict__ alpha_re, const float* __restrict__ alpha_im,
    const float* __restrict__ theta_t, const float* __restrict__ theta_r,
    float* __restrict__ out, int interleaved)
{
    __shared__ float sAr[KC][TILE][2];
    __shared__ float sAt[KC][TILE][2];
    const int tid = threadIdx.x;
    const int bid = blockIdx.x;
    const int r0 = (bid / (N_T / TILE)) * TILE;
    const int t0 = (bid % (N_T / TILE)) * TILE;
    const int tx = tid & 15;
    const int ty = tid >> 4;
    float accRe[4][4] = {{0.f}};
    float accIm[4][4] = {{0.f}};
    const float C = 1.0f / 128.0f;
    const float PI = 3.14159265358979323846f;
    for (int lc = 0; lc < L_RAYS; lc += KC) {
        __syncthreads();
        for (int idx = tid; idx < KC * TILE; idx += 256) {
            const int ll = idx >> 6;
            const int rr = idx & 63;
            const int l = lc + ll;
            const float are = alpha_re[l] * C;
            const float aim = alpha_im[l] * C;
            const float srr = sinf(theta_r[l]);
            const float stt = sinf(theta_t[l]);
            {
                float x = (float)(r0 + rr) * srr;
                float f = x - 2.0f * rintf(0.5f * x);
                float s, c;
                __sincosf(PI * f, &s, &c);
                sAr[ll][rr][0] = are * c - aim * s;
                sAr[ll][rr][1] = are * s + aim * c;
            }
            {
                float x = (float)(t0 + rr) * stt;
                float f = x - 2.0f * rintf(0.5f * x);
                float s, c;
                __sincosf(PI * f, &s, &c);
                sAt[ll][rr][0] = c;
                sAt[ll][rr][1] = s;
            }
        }
        __syncthreads();
        #pragma unroll 4
        for (int ll = 0; ll < KC; ++ll) {
            const float4 arv0 = *reinterpret_cast<const float4*>(&sAr[ll][ty * 4 + 0][0]);
            const float4 arv1 = *reinterpret_cast<const float4*>(&sAr[ll][ty * 4 + 2][0]);
            const float4 atv0 = *reinterpret_cast<const float4*>(&sAt[ll][tx * 4 + 0][0]);
            const float4 atv1 = *reinterpret_cast<const float4*>(&sAt[ll][tx * 4 + 2][0]);
            const float arre[4] = {arv0.x, arv0.z, arv1.x, arv1.z};
            const float arim[4] = {arv0.y, arv0.w, arv1.y, arv1.w};
            const float atre[4] = {atv0.x, atv0.z, atv1.x, atv1.z};
            const float atim[4] = {atv0.y, atv0.w, atv1.y, atv1.w};
            #pragma unroll
            for (int i = 0; i < 4; ++i)
                #pragma unroll
                for (int j = 0; j < 4; ++j) {
                    accRe[i][j] = fmaf(arre[i], atre[j], fmaf(arim[i], atim[j], accRe[i][j]));
                    accIm[i][j] = fmaf(arim[i], atre[j], fmaf(-arre[i], atim[j], accIm[i][j]));
                }
        }
    }
    #pragma unroll
    for (int i = 0; i < 4; ++i) {
        const int r = r0 + ty * 4 + i;
        #pragma unroll
        for (int j = 0; j < 4; ++j) {
            const int t = t0 + tx * 4 + j;
            if (interleaved) {
                out[2 * (r * N_T + t) + 0] = accRe[i][j];
                out[2 * (r * N_T + t) + 1] = accIm[i][j];
            } else {
                out[r * N_T + t] = accRe[i][j];
            }
        }
    }
}

// ------------------------------------------------------------- launch
extern "C" void kernel_launch(void* const* d_in, const int* in_sizes, int n_in,
                              void* d_out, int out_size, void* d_ws, size_t ws_size,
                              hipStream_t stream) {
    const float* alpha_re = (const float*)d_in[0];
    const float* alpha_im = (const float*)d_in[1];
    const float* theta_t  = (const float*)d_in[2];
    const float* theta_r  = (const float*)d_in[3];
    float* out = (float*)d_out;

    const int interleaved = (out_size >= 2 * N_R * N_T) ? 1 : 0;
    const size_t offP    = 0;
    const size_t offPre1 = (size_t)SPLITK * N_R * N_T * 4;          // 32 MB
    const size_t offPre2 = offPre1 + (size_t)L_RAYS * 16;           // +128 KB
    const size_t need    = offPre2 + (size_t)L_RAYS * 16;           // +128 KB

    if (interleaved || ws_size < need) {
        const int nblocks = (N_R / TILE) * (N_T / TILE);
        geo_channel_fallback<<<nblocks, 256, 0, stream>>>(
            alpha_re, alpha_im, theta_t, theta_r, out, interleaved);
        return;
    }

    char* ws = (char*)d_ws;
    float* P = (float*)(ws + offP);
    float4* pre1 = (float4*)(ws + offPre1);
    float4* pre2 = (float4*)(ws + offPre2);

    precomp_kernel<<<(L_RAYS + 255) / 256, 256, 0, stream>>>(
        alpha_re, alpha_im, theta_t, theta_r, pre1, pre2);
    fused_gemm_kernel<<<NTILES * SPLITK, 256, 0, stream>>>(pre1, pre2, P);
    reduce_kernel<<<(N_R * N_T / 4) / 256, 256, 0, stream>>>(
        (const f32x4*)P, (f32x4*)out);
}

// Round 8
// 90.861 us; speedup vs baseline: 1.1099x; 1.1099x over previous
//
#include <hip/hip_runtime.h>
#include <math.h>
#include <stdint.h>

// H[r,t] = (1/128) * sum_l alpha_l * exp(j*pi*r*sin(theta_r_l)) * exp(-j*pi*t*sin(theta_t_l))
// Output: out_size == 1024*1024 -> Re(H).
// Re(H) = A * B^T with K interleaved as (re,im) pairs per ray:
//   A[r][2l]   = C*(ar*cos(phi) - ai*sin(phi)),  phi = pi*r*sin(theta_r_l), C = 1/128
//   A[r][2l+1] = C*(ar*sin(phi) + ai*cos(phi))
//   B[t][2l]   = cos(psi),  psi = pi*t*sin(theta_t_l)
//   B[t][2l+1] = sin(psi)
// r8 = r5 skeleton composed with r6-validated pieces only:
//   - A frags {wave, wave+4} in LDS (r5 layout); frag wave+4 chained from frag
//     wave by d64 = e^{j*2pi*32*sr} (r6-validated chain, halves A sincos)
//   - B fully in registers, wc-matched gen (r6-validated): base sincos at col
//     wc*64+rsub, 3 chains of +16 cols via d16 = e^{j*2pi*8*st}; no Bs LDS
//   - per-ray params sP + deltas sD staged in LDS pre-loop (r5 pattern)
//   - two barriers per K-step protect As only; fp32 split-K partials + reduce
// Trans ops/thread-kt: 32 (r5) -> 16. LDS b128/thread-kt: 12 -> 6.

#define N_T 1024
#define N_R 1024
#define L_RAYS 8192

#define BM 128
#define BN 128
#define BK 32
#define NTILES 64          // 8x8 tile grid
#define SPLITK 16
#define RAYS_PER_BLK 512   // L_RAYS / SPLITK
#define KSTEPS 32          // RAYS_PER_BLK*2 / BK

typedef __attribute__((ext_vector_type(8))) short bf16x8;
typedef __attribute__((ext_vector_type(4))) float f32x4;
typedef __attribute__((ext_vector_type(4))) unsigned int u32x4;

static __device__ __forceinline__ unsigned pk_bf16(float lo, float hi) {
    unsigned o;
    asm("v_cvt_pk_bf16_f32 %0, %1, %2" : "=v"(o) : "v"(lo), "v"(hi));
    return o;
}

// ------------------------------------------------------------- fused GEMM
// grid = 64 tiles * SPLITK = 1024 blocks (4/CU), 256 threads (4 waves, 2x2).
// LDS fragment-linear (A only): fragment f (16 rows x 32 k) occupies bytes
// [f*1024, f*1024+1024); lane slot s holds row (f*16 + (s&15)),
// k = (s>>4)*8 .. +7 -> matches mfma_f32_16x16x32_bf16 operand layout; both
// gen ds_write_b128 and fragment ds_read_b128 are lane-linear: zero conflicts.
// B-operand slots are thread-local by construction (gen cols == consume cols).
__global__ __launch_bounds__(256, 3) void fused_gemm_kernel(
    const float* __restrict__ alpha_re, const float* __restrict__ alpha_im,
    const float* __restrict__ theta_t, const float* __restrict__ theta_r,
    float* __restrict__ Pout)  // [SPLITK][N_R][N_T] fp32 partials
{
    __shared__ unsigned short As[BM * BK];   // 8 KB: A frags 0..7
    __shared__ float4 sP[RAYS_PER_BLK];      // 8 KB: (0.5*sin_r, 0.5*sin_t, ar*C, ai*C)
    __shared__ float4 sD[RAYS_PER_BLK];      // 8 KB: (dA64.re, dA64.im, dB16.re, dB16.im)

    const int tid  = threadIdx.x;
    const int wave = tid >> 6;          // 0..3
    const int lane = tid & 63;
    const int bid  = blockIdx.x;
    const int tile = bid & (NTILES - 1);
    const int sk   = bid >> 6;          // split-K slice 0..15
    const int r0 = (tile >> 3) * BM;
    const int c0 = (tile & 7) * BN;

    // per-ray parameters + fragment-step deltas for this K-slice.
    // phase slope per row/col: 0.5*sin (revolutions).
    // A chain step = +64 rows -> 32*sin rev; B chain step = +16 cols -> 8*sin rev.
    for (int i = tid; i < RAYS_PER_BLK; i += 256) {
        const int l = sk * RAYS_PER_BLK + i;
        const float C = 0.0078125f;     // 1/128
        const float sr = sinf(theta_r[l]);
        const float st = sinf(theta_t[l]);
        sP[i] = make_float4(0.5f * sr, 0.5f * st, alpha_re[l] * C, alpha_im[l] * C);
        float uA = 32.0f * sr;  uA -= rintf(uA);
        float uB = 8.0f  * st;  uB -= rintf(uB);
        sD[i] = make_float4(__builtin_amdgcn_cosf(uA), __builtin_amdgcn_sinf(uA),
                            __builtin_amdgcn_cosf(uB), __builtin_amdgcn_sinf(uB));
    }

    f32x4 acc[4][4];
    #pragma unroll
    for (int m = 0; m < 4; ++m)
        #pragma unroll
        for (int n = 0; n < 4; ++n)
            acc[m][n] = (f32x4){0.f, 0.f, 0.f, 0.f};

    const int k8   = lane >> 4;         // ray sub-group 0..3
    const int rsub = lane & 15;         // row/col within fragment
    const int wr = wave >> 1;           // 0..1: row half (64 rows)
    const int wc = wave & 1;            // 0..1: col half (64 cols)

    // A base row: fragment `wave` (r5 mapping); frag wave+4 = +64 rows (chained)
    const float rwA = (float)(r0 + wave * 16 + rsub);
    // B base col: fragment wc*4 (thread-local consume set); +16 per chain step
    const float twB = (float)(c0 + wc * 64 + rsub);

    char* Ab = reinterpret_cast<char*>(&As[0]);

    for (int kt = 0; kt < KSTEPS; ++kt) {
        __syncthreads();   // kt=0: sP/sD ready; kt>0: prev A-frag reads done (WAR)

        const int lidx = kt * 16 + k8 * 4;   // local ray base for this k-group
        unsigned oa0[4], oa1[4];             // A frags wave, wave+4
        unsigned ob[4][4];                   // B frags wc*4+q  [q][ray j]
        #pragma unroll
        for (int j = 0; j < 4; ++j) {
            const float4 p = sP[lidx + j];
            const float4 d = sD[lidx + j];
            // --- A: base phasor * alpha at row rwA, chain +64 rows via (d.x,d.y)
            float u = rwA * p.x;  u -= rintf(u);
            const float asn = __builtin_amdgcn_sinf(u);
            const float acs = __builtin_amdgcn_cosf(u);
            float re = p.z * acs - p.w * asn;
            float im = p.z * asn + p.w * acs;
            oa0[j] = pk_bf16(re, im);
            {
                const float t = re * d.x - im * d.y;
                im = re * d.y + im * d.x;
                re = t;
            }
            oa1[j] = pk_bf16(re, im);
            // --- B: unit phasor at col twB, chain +16 cols via (d.z,d.w)
            float ub = twB * p.y;  ub -= rintf(ub);
            float bim = __builtin_amdgcn_sinf(ub);
            float bre = __builtin_amdgcn_cosf(ub);
            ob[0][j] = pk_bf16(bre, bim);
            #pragma unroll
            for (int q = 1; q < 4; ++q) {
                const float t = bre * d.z - bim * d.w;
                bim = bre * d.w + bim * d.z;
                bre = t;
                ob[q][j] = pk_bf16(bre, bim);
            }
        }
        // write A fragments (lane-linear b128, zero conflicts)
        *reinterpret_cast<u32x4*>(Ab + (wave + 0) * 1024 + lane * 16)
            = (u32x4){oa0[0], oa0[1], oa0[2], oa0[3]};
        *reinterpret_cast<u32x4*>(Ab + (wave + 4) * 1024 + lane * 16)
            = (u32x4){oa1[0], oa1[1], oa1[2], oa1[3]};
        __syncthreads();   // A tile visible

        // ---- consume: a from LDS, b from this thread's registers
        bf16x8 a[4], b[4];
        #pragma unroll
        for (int n = 0; n < 4; ++n) {
            const u32x4 t = (u32x4){ob[n][0], ob[n][1], ob[n][2], ob[n][3]};
            b[n] = __builtin_bit_cast(bf16x8, t);
        }
        #pragma unroll
        for (int m = 0; m < 4; ++m)
            a[m] = *reinterpret_cast<const bf16x8*>(Ab + (wr * 4 + m) * 1024 + lane * 16);
        __builtin_amdgcn_s_setprio(1);
        #pragma unroll
        for (int m = 0; m < 4; ++m)
            #pragma unroll
            for (int n = 0; n < 4; ++n)
                acc[m][n] = __builtin_amdgcn_mfma_f32_16x16x32_bf16(a[m], b[n], acc[m][n], 0, 0, 0);
        __builtin_amdgcn_s_setprio(0);
    }

    // C/D layout (m89/m91): col = lane&15, row = (lane>>4)*4 + reg
    float* P = Pout + (size_t)sk * (N_R * N_T);
    const int crow0 = r0 + wr * 64 + (lane >> 4) * 4;
    const int ccol0 = c0 + wc * 64 + (lane & 15);
    #pragma unroll
    for (int m = 0; m < 4; ++m)
        #pragma unroll
        for (int n = 0; n < 4; ++n)
            #pragma unroll
            for (int j = 0; j < 4; ++j)
                P[(size_t)(crow0 + m * 16 + j) * N_T + ccol0 + n * 16] = acc[m][n][j];
}

// ------------------------------------------------------------- split-K reduce
__global__ __launch_bounds__(256) void reduce_kernel(
    const f32x4* __restrict__ P, f32x4* __restrict__ out)
{
    const int i = blockIdx.x * 256 + threadIdx.x;   // over N_R*N_T/4
    const int n4 = (N_R * N_T) / 4;
    f32x4 s = P[i];
    #pragma unroll
    for (int sk = 1; sk < SPLITK; ++sk) s += P[(size_t)sk * n4 + i];
    out[i] = s;
}

// ------------------------------------------------------------- fp32 fallback
#define TILE 64
#define KC 32
__global__ __launch_bounds__(256) void geo_channel_fallback(
    const float* __restrict__ alpha_re, const float* __restrict__ alpha_im,
    const float* __restrict__ theta_t, const float* __restrict__ theta_r,
    float* __restrict__ out, int interleaved)
{
    __shared__ float sAr[KC][TILE][2];
    __shared__ float sAt[KC][TILE][2];
    const int tid = threadIdx.x;
    const int bid = blockIdx.x;
    const int r0 = (bid / (N_T / TILE)) * TILE;
    const int t0 = (bid % (N_T / TILE)) * TILE;
    const int tx = tid & 15;
    const int ty = tid >> 4;
    float accRe[4][4] = {{0.f}};
    float accIm[4][4] = {{0.f}};
    const float C = 1.0f / 128.0f;
    const float PI = 3.14159265358979323846f;
    for (int lc = 0; lc < L_RAYS; lc += KC) {
        __syncthreads();
        for (int idx = tid; idx < KC * TILE; idx += 256) {
            const int ll = idx >> 6;
            const int rr = idx & 63;
            const int l = lc + ll;
            const float are = alpha_re[l] * C;
            const float aim = alpha_im[l] * C;
            const float srr = sinf(theta_r[l]);
            const float stt = sinf(theta_t[l]);
            {
                float x = (float)(r0 + rr) * srr;
                float f = x - 2.0f * rintf(0.5f * x);
                float s, c;
                __sincosf(PI * f, &s, &c);
                sAr[ll][rr][0] = are * c - aim * s;
                sAr[ll][rr][1] = are * s + aim * c;
            }
            {
                float x = (float)(t0 + rr) * stt;
                float f = x - 2.0f * rintf(0.5f * x);
                float s, c;
                __sincosf(PI * f, &s, &c);
                sAt[ll][rr][0] = c;
                sAt[ll][rr][1] = s;
            }
        }
        __syncthreads();
        #pragma unroll 4
        for (int ll = 0; ll < KC; ++ll) {
            const float4 arv0 = *reinterpret_cast<const float4*>(&sAr[ll][ty * 4 + 0][0]);
            const float4 arv1 = *reinterpret_cast<const float4*>(&sAr[ll][ty * 4 + 2][0]);
            const float4 atv0 = *reinterpret_cast<const float4*>(&sAt[ll][tx * 4 + 0][0]);
            const float4 atv1 = *reinterpret_cast<const float4*>(&sAt[ll][tx * 4 + 2][0]);
            const float arre[4] = {arv0.x, arv0.z, arv1.x, arv1.z};
            const float arim[4] = {arv0.y, arv0.w, arv1.y, arv1.w};
            const float atre[4] = {atv0.x, atv0.z, atv1.x, atv1.z};
            const float atim[4] = {atv0.y, atv0.w, atv1.y, atv1.w};
            #pragma unroll
            for (int i = 0; i < 4; ++i)
                #pragma unroll
                for (int j = 0; j < 4; ++j) {
                    accRe[i][j] = fmaf(arre[i], atre[j], fmaf(arim[i], atim[j], accRe[i][j]));
                    accIm[i][j] = fmaf(arim[i], atre[j], fmaf(-arre[i], atim[j], accIm[i][j]));
                }
        }
    }
    #pragma unroll
    for (int i = 0; i < 4; ++i) {
        const int r = r0 + ty * 4 + i;
        #pragma unroll
        for (int j = 0; j < 4; ++j) {
            const int t = t0 + tx * 4 + j;
            if (interleaved) {
                out[2 * (r * N_T + t) + 0] = accRe[i][j];
                out[2 * (r * N_T + t) + 1] = accIm[i][j];
            } else {
                out[r * N_T + t] = accRe[i][j];
            }
        }
    }
}

// ------------------------------------------------------------- launch
extern "C" void kernel_launch(void* const* d_in, const int* in_sizes, int n_in,
                              void* d_out, int out_size, void* d_ws, size_t ws_size,
                              hipStream_t stream) {
    const float* alpha_re = (const float*)d_in[0];
    const float* alpha_im = (const float*)d_in[1];
    const float* theta_t  = (const float*)d_in[2];
    const float* theta_r  = (const float*)d_in[3];
    float* out = (float*)d_out;

    const int interleaved = (out_size >= 2 * N_R * N_T) ? 1 : 0;
    const size_t needP = (size_t)SPLITK * N_R * N_T * 4;   // 64 MB fp32 partials

    if (interleaved || ws_size < needP) {
        const int nblocks = (N_R / TILE) * (N_T / TILE);
        geo_channel_fallback<<<nblocks, 256, 0, stream>>>(
            alpha_re, alpha_im, theta_t, theta_r, out, interleaved);
        return;
    }

    float* P = (float*)d_ws;
    fused_gemm_kernel<<<NTILES * SPLITK, 256, 0, stream>>>(
        alpha_re, alpha_im, theta_t, theta_r, P);
    reduce_kernel<<<(N_R * N_T / 4) / 256, 256, 0, stream>>>(
        (const f32x4*)P, (f32x4*)out);
}